// Round 7
// baseline (295.378 us; speedup 1.0000x reference)
//
#include <hip/hip_runtime.h>
#include <hip/hip_bf16.h>
#include <hip/hip_cooperative_groups.h>

namespace cg = cooperative_groups;

typedef unsigned short u16;
typedef __attribute__((ext_vector_type(8))) short short8;
typedef __attribute__((ext_vector_type(4))) float f32x4;

#define B_ 32
#define L_ 1024
#define D_ 1024
#define E_ 100
#define E1_ 101
#define M2_ (B_ * E1_)     // 3232 entity rows (incl. none-entity)
#define M2P_ 3328          // padded to 26*128 for the 128-row MFMA tiles
#define QBLK_ 32
#define NBLK3_ 7           // tiles that can contain valid rows (Q_MAX=200 < 7*32)
#define NBLKS_ 512         // cooperative grid: 2 blocks/CU x 256 CU (64 KB LDS each)
#define NU0_ (M2_ + 1024 + 800)   // phase-0 units: encode + wsplit + light zerofill

#define MFMA16(a, b, c) __builtin_amdgcn_mfma_f32_16x16x32_bf16((a), (b), (c), 0, 0, 0)

__device__ __forceinline__ void split2(float x, u16& h, u16& l) {
    __hip_bfloat16 bh = __float2bfloat16(x);          // RN
    float r = x - __bfloat162float(bh);
    __hip_bfloat16 bl = __float2bfloat16(r);
    h = __builtin_bit_cast(u16, bh);
    l = __builtin_bit_cast(u16, bl);
}

// async global->LDS, 16B per lane; LDS dest = wave-uniform base + lane*16
__device__ __forceinline__ void gload16(const void* g, void* l) {
    __builtin_amdgcn_global_load_lds(
        (const __attribute__((address_space(1))) unsigned int*)g,
        (__attribute__((address_space(3))) unsigned int*)l, 16, 0, 0);
}

struct P0s { float red4[4]; };
struct P1s { u16 Ah[128 * 64]; u16 Al[128 * 64]; u16 Bh[128 * 64]; u16 Bl[128 * 64]; };
struct P2s { u16 Ah[32 * 64]; u16 Al[32 * 64]; u16 Bh[128 * 64]; u16 Bl[128 * 64];
             float Ss[32 * 113]; float red[QBLK_][8]; };

// ---------------- unit: encode one (b,e) entity row -> enc hi/lo + ep_last
__device__ __forceinline__ void d_encode(int id, int tid,
                                         const float* __restrict__ q_enc,
                                         const float* __restrict__ none_ent,
                                         const float* __restrict__ W,
                                         const float* __restrict__ bias,
                                         const int* __restrict__ ranges,
                                         u16* __restrict__ enc_hi, u16* __restrict__ enc_lo,
                                         float* __restrict__ ep_last, float* red4) {
    int b = id / E1_, e = id - b * E1_;
    int c = tid * 4;
    float4 acc;
    if (e == E_) {
        acc = *(const float4*)&none_ent[c];
    } else {
        acc = make_float4(0.f, 0.f, 0.f, 0.f);
        int r0 = ranges[(b * E_ + e) * 2 + 0];
        int r1 = ranges[(b * E_ + e) * 2 + 1];
        for (int l = r0 + 1; l < r1; ++l) {
            float4 v = *(const float4*)&q_enc[((size_t)b * L_ + l) * D_ + c];
            acc.x += v.x; acc.y += v.y; acc.z += v.z; acc.w += v.w;
        }
    }
    union { u16 u[4]; float2 f; } ph, pl;
    split2(acc.x, ph.u[0], pl.u[0]); split2(acc.y, ph.u[1], pl.u[1]);
    split2(acc.z, ph.u[2], pl.u[2]); split2(acc.w, ph.u[3], pl.u[3]);
    *(float2*)&enc_hi[(size_t)id * 1024 + c] = ph.f;
    *(float2*)&enc_lo[(size_t)id * 1024 + c] = pl.f;
    const float* w1k = W + (size_t)1024 * 1024;
    float4 wv = *(const float4*)&w1k[c];
    float s = acc.x * wv.x + acc.y * wv.y + acc.z * wv.z + acc.w * wv.w;
    #pragma unroll
    for (int off = 32; off; off >>= 1) s += __shfl_down(s, off);
    if ((tid & 63) == 0) red4[tid >> 6] = s;
    __syncthreads();
    if (tid == 0) ep_last[id] = red4[0] + red4[1] + red4[2] + red4[3] + bias[1024];
    __syncthreads();   // protect red4 before next grid-stride unit reuses it
}

// ---------------- unit: split one W row -> bf16 hi/lo
__device__ __forceinline__ void d_wsplit(int r, int tid, const float* __restrict__ W,
                                         u16* __restrict__ w_hi, u16* __restrict__ w_lo) {
    int c = tid * 4;
    float4 v = *(const float4*)&W[(size_t)r * 1024 + c];
    union { u16 u[4]; float2 f; } ph, pl;
    split2(v.x, ph.u[0], pl.u[0]); split2(v.y, ph.u[1], pl.u[1]);
    split2(v.z, ph.u[2], pl.u[2]); split2(v.w, ph.u[3], pl.u[3]);
    *(float2*)&w_hi[(size_t)r * 1024 + c] = ph.f;
    *(float2*)&w_lo[(size_t)r * 1024 + c] = pl.f;
}

// ---------------- unit: zero one co_att tile (32 rows x 101)
__device__ __forceinline__ void d_zerotile(int b, int mt, int tid, float* __restrict__ co_att) {
    float* base = &co_att[((size_t)b * L_ + mt * QBLK_) * E1_];
    float4 z = make_float4(0.f, 0.f, 0.f, 0.f);
    for (int i = tid; i < QBLK_ * E1_ / 4; i += 256)
        *(float4*)&base[i * 4] = z;
}

// ---------------- unit: one 128x128 entproj tile (3-term bf16 MFMA, gload_lds staging)
__device__ __forceinline__ void d_entproj(int mt, int nt, int tid,
                                          const u16* __restrict__ A_hi, const u16* __restrict__ A_lo,
                                          const u16* __restrict__ B_hi, const u16* __restrict__ B_lo,
                                          const float* __restrict__ bias,
                                          u16* __restrict__ ep_hi, u16* __restrict__ ep_lo,
                                          P1s* sm) {
    int m0 = mt * 128, n0 = nt * 128;
    int w = tid >> 6, lane = tid & 63, lr = lane & 15, lg = lane >> 4;
    int wr = w >> 1, wc = w & 1;
    f32x4 zero = {0.f, 0.f, 0.f, 0.f};
    f32x4 acc[4][4];
    #pragma unroll
    for (int i = 0; i < 4; ++i)
        #pragma unroll
        for (int j = 0; j < 4; ++j) acc[i][j] = zero;
    int sb = w * 256;                 // wave's slot base (of 1024 slots/array)
    for (int k0 = 0; k0 < 1024; k0 += 64) {
        #pragma unroll
        for (int j = 0; j < 4; ++j) {
            int slot = sb + j * 64 + lane;      // slot = r*8 + s
            int r = slot >> 3, s = slot & 7;
            int g = (s ^ (r & 7)) << 3;         // pre-swizzled source column group
            size_t ga = (size_t)(m0 + r) * 1024 + k0 + g;
            size_t gb = (size_t)(n0 + r) * 1024 + k0 + g;
            int ld = (sb + j * 64) * 8;         // wave-uniform LDS base (u16 idx)
            gload16(&A_hi[ga], &sm->Ah[ld]);
            gload16(&A_lo[ga], &sm->Al[ld]);
            gload16(&B_hi[gb], &sm->Bh[ld]);
            gload16(&B_lo[gb], &sm->Bl[ld]);
        }
        __syncthreads();
        #pragma unroll
        for (int half = 0; half < 2; ++half) {
            int sk = half * 4 + lg;
            short8 a_h[4], a_l[4], b_h[4], b_l[4];
            #pragma unroll
            for (int mf = 0; mf < 4; ++mf) {
                int R = wr * 64 + mf * 16 + lr;
                int ad = R * 64 + ((sk ^ (R & 7)) << 3);
                a_h[mf] = __builtin_bit_cast(short8, *(const float4*)&sm->Ah[ad]);
                a_l[mf] = __builtin_bit_cast(short8, *(const float4*)&sm->Al[ad]);
            }
            #pragma unroll
            for (int nf = 0; nf < 4; ++nf) {
                int R = wc * 64 + nf * 16 + lr;
                int ad = R * 64 + ((sk ^ (R & 7)) << 3);
                b_h[nf] = __builtin_bit_cast(short8, *(const float4*)&sm->Bh[ad]);
                b_l[nf] = __builtin_bit_cast(short8, *(const float4*)&sm->Bl[ad]);
            }
            #pragma unroll
            for (int mf = 0; mf < 4; ++mf)
                #pragma unroll
                for (int nf = 0; nf < 4; ++nf) {
                    acc[mf][nf] = MFMA16(a_h[mf], b_h[nf], acc[mf][nf]);
                    acc[mf][nf] = MFMA16(a_h[mf], b_l[nf], acc[mf][nf]);
                    acc[mf][nf] = MFMA16(a_l[mf], b_h[nf], acc[mf][nf]);
                }
        }
        __syncthreads();
    }
    #pragma unroll
    for (int mf = 0; mf < 4; ++mf)
        #pragma unroll
        for (int nf = 0; nf < 4; ++nf)
            #pragma unroll
            for (int reg = 0; reg < 4; ++reg) {
                int m = m0 + wr * 64 + mf * 16 + lg * 4 + reg;
                if (m < M2_) {
                    int n = n0 + wc * 64 + nf * 16 + lr;
                    float v = acc[mf][nf][reg] + bias[n];
                    u16 h, l;
                    split2(v, h, l);
                    ep_hi[(size_t)m * 1024 + n] = h;
                    ep_lo[(size_t)m * 1024 + n] = l;
                }
            }
}

// ---------------- unit: one heavy scores tile (MFMA + softmax + co_att + partial)
__device__ __forceinline__ void d_scores(int b, int mt, int tid,
                                         const float* __restrict__ q_enc,
                                         const float* __restrict__ hint,
                                         const u16* __restrict__ ep_hi, const u16* __restrict__ ep_lo,
                                         const float* __restrict__ ep_last,
                                         const int* __restrict__ qlen,
                                         float* __restrict__ co_att,
                                         float* __restrict__ partial,
                                         P2s* sm) {
    int l0 = mt * QBLK_;
    int qn = qlen[b];
    if (l0 >= qn) {
        d_zerotile(b, mt, tid, co_att);
        for (int e = tid; e < E1_; e += 256)
            partial[((size_t)b * NBLK3_ + mt) * E1_ + e] = 0.f;
        return;
    }
    int w = tid >> 6, lane = tid & 63, lr = lane & 15, lg = lane >> 4;
    int mf = w & 1, nb = (w >> 1) * 4, nc = (w >> 1) ? 3 : 4;
    int sb = w * 256;
    f32x4 zero = {0.f, 0.f, 0.f, 0.f};
    f32x4 acc[4] = {zero, zero, zero, zero};
    for (int k0 = 0; k0 < 1024; k0 += 64) {
        {   // B: 128 rows x 64 k via gload_lds (rows >100 are finite garbage, masked later)
            #pragma unroll
            for (int j = 0; j < 4; ++j) {
                int slot = sb + j * 64 + lane;
                int r = slot >> 3, s = slot & 7;
                int g = (s ^ (r & 7)) << 3;
                size_t gb = ((size_t)b * E1_ + r) * 1024 + k0 + g;
                int ld = (sb + j * 64) * 8;
                gload16(&ep_hi[gb], &sm->Bh[ld]);
                gload16(&ep_lo[gb], &sm->Bl[ld]);
            }
        }
        {   // A: 32 rows x 64 k, split fp32 -> hi/lo on the fly (1 slot per thread)
            int r = tid >> 3, s = tid & 7;
            const float* src = &q_enc[((size_t)b * L_ + l0 + r) * D_ + k0 + s * 8];
            float4 x0 = *(const float4*)src, x1 = *(const float4*)(src + 4);
            float xs[8] = {x0.x, x0.y, x0.z, x0.w, x1.x, x1.y, x1.z, x1.w};
            short8 hv, lv;
            #pragma unroll
            for (int j = 0; j < 8; ++j) {
                u16 hh, ll;
                split2(xs[j], hh, ll);
                hv[j] = (short)hh; lv[j] = (short)ll;
            }
            int dst = r * 64 + ((s ^ (r & 7)) << 3);
            *(float4*)&sm->Ah[dst] = __builtin_bit_cast(float4, hv);
            *(float4*)&sm->Al[dst] = __builtin_bit_cast(float4, lv);
        }
        __syncthreads();
        #pragma unroll
        for (int ks = 0; ks < 64; ks += 32) {
            int sk = (ks >> 3) + lg;
            int rA = mf * 16 + lr;
            int adA = rA * 64 + ((sk ^ (rA & 7)) << 3);
            short8 ah = __builtin_bit_cast(short8, *(const float4*)&sm->Ah[adA]);
            short8 al = __builtin_bit_cast(short8, *(const float4*)&sm->Al[adA]);
            #pragma unroll
            for (int nf = 0; nf < 4; ++nf) {
                if (nf < nc) {
                    int rB = (nb + nf) * 16 + lr;
                    int adB = rB * 64 + ((sk ^ (rB & 7)) << 3);
                    short8 bh = __builtin_bit_cast(short8, *(const float4*)&sm->Bh[adB]);
                    short8 bl = __builtin_bit_cast(short8, *(const float4*)&sm->Bl[adB]);
                    acc[nf] = MFMA16(ah, bh, acc[nf]);
                    acc[nf] = MFMA16(ah, bl, acc[nf]);
                    acc[nf] = MFMA16(al, bh, acc[nf]);
                }
            }
        }
        __syncthreads();
    }
    #pragma unroll
    for (int nf = 0; nf < 4; ++nf)
        if (nf < nc) {
            #pragma unroll
            for (int reg = 0; reg < 4; ++reg)
                sm->Ss[(mf * 16 + lg * 4 + reg) * 113 + (nb + nf) * 16 + lr] = acc[nf][reg];
        }
    __syncthreads();
    // ---- softmax over 101 entities per row
    int l = tid & 31, eg = tid >> 5;
    float h = hint[(size_t)b * L_ + l0 + l];
    float sc[13];
    #pragma unroll
    for (int j = 0; j < 13; ++j) {
        int e = eg + 8 * j;
        sc[j] = (e < E1_) ? (sm->Ss[l * 113 + e] + h * ep_last[b * E1_ + e]) : -3.4e38f;
    }
    float mloc = -3.4e38f;
    #pragma unroll
    for (int j = 0; j < 13; ++j) mloc = fmaxf(mloc, sc[j]);
    sm->red[l][eg] = mloc;
    __syncthreads();
    float m = sm->red[l][0];
    #pragma unroll
    for (int k = 1; k < 8; ++k) m = fmaxf(m, sm->red[l][k]);
    __syncthreads();
    float p[13];
    float sloc = 0.f;
    #pragma unroll
    for (int j = 0; j < 13; ++j) {
        p[j] = 0.f;
        if (eg + 8 * j < E1_) { p[j] = __expf(sc[j] - m); sloc += p[j]; }
    }
    sm->red[l][eg] = sloc;
    __syncthreads();
    float ssum = 0.f;
    #pragma unroll
    for (int k = 0; k < 8; ++k) ssum += sm->red[l][k];
    float inv = 1.f / ssum;
    bool valid = (l0 + l) < qn;
    float maskv = valid ? inv : 0.f;
    float* row = &co_att[((size_t)b * L_ + l0 + l) * E1_];
    #pragma unroll
    for (int j = 0; j < 13; ++j) {
        int e = eg + 8 * j;
        if (e < E1_) row[e] = p[j] * maskv;
    }
    #pragma unroll
    for (int j = 0; j < 13; ++j) {
        int e = eg + 8 * j;
        float v = (e < E1_) ? p[j] * maskv : 0.f;
        v += __shfl_xor(v, 1);  v += __shfl_xor(v, 2);
        v += __shfl_xor(v, 4);  v += __shfl_xor(v, 8);
        v += __shfl_xor(v, 16);
        if ((tid & 31) == 0 && e < E1_)
            partial[((size_t)b * NBLK3_ + mt) * E1_ + e] = v;
    }
}

// ---------------- unit: att[b,:] = min(sum of 7 partials, 1)
__device__ __forceinline__ void d_att(int b, int tid, const float* __restrict__ partial,
                                      float* __restrict__ att) {
    for (int e = tid; e < E_; e += 256) {
        float s = 0.f;
        #pragma unroll
        for (int k = 0; k < NBLK3_; ++k) s += partial[((size_t)b * NBLK3_ + k) * E1_ + e];
        att[b * E_ + e] = fminf(s, 1.f);
    }
}

// ================= cooperative mega-kernel: all phases, grid.sync between =================
__global__ __launch_bounds__(256, 2) void k_mega(const float* __restrict__ q_enc,
                                                 const float* __restrict__ hint,
                                                 const float* __restrict__ W,
                                                 const float* __restrict__ bias,
                                                 const float* __restrict__ none_ent,
                                                 const int* __restrict__ qlen,
                                                 const int* __restrict__ ranges,
                                                 u16* __restrict__ enc_hi, u16* __restrict__ enc_lo,
                                                 u16* __restrict__ w_hi, u16* __restrict__ w_lo,
                                                 u16* __restrict__ ep_hi, u16* __restrict__ ep_lo,
                                                 float* __restrict__ ep_last,
                                                 float* __restrict__ co_att,
                                                 float* __restrict__ partial,
                                                 float* __restrict__ att) {
    __shared__ __attribute__((aligned(16))) union { P0s p0; P1s p1; P2s p2; } sm;
    cg::grid_group grid = cg::this_grid();
    int bid = blockIdx.x, tid = threadIdx.x;
    // ---- P0: encode | wsplit | zero light co_att tiles
    for (int u = bid; u < NU0_; u += NBLKS_) {
        if (u < M2_) {
            d_encode(u, tid, q_enc, none_ent, W, bias, ranges, enc_hi, enc_lo, ep_last, sm.p0.red4);
        } else if (u < M2_ + 1024) {
            d_wsplit(u - M2_, tid, W, w_hi, w_lo);
        } else {
            int lt = u - M2_ - 1024;                 // 0..799
            d_zerotile(lt & 31, NBLK3_ + (lt >> 5), tid, co_att);
        }
    }
    grid.sync();
    // ---- P1: entproj, 208 tiles (n fastest -> same n-panel per XCD)
    if (bid < 208)
        d_entproj(bid >> 3, bid & 7, tid, enc_hi, enc_lo, w_hi, w_lo, bias, ep_hi, ep_lo, &sm.p1);
    grid.sync();
    // ---- P2: heavy score tiles, 224 units (b fastest -> batch's ep L2-local per XCD)
    if (bid < B_ * NBLK3_)
        d_scores(bid & 31, bid >> 5, tid, q_enc, hint, ep_hi, ep_lo, ep_last, qlen,
                 co_att, partial, &sm.p2);
    grid.sync();
    // ---- P3: att reduction (fixed order, deterministic)
    if (bid < B_)
        d_att(bid, tid, partial, att);
}

// ================= fallback kernels (same device fns) if cooperative launch fails ========
__global__ __launch_bounds__(256) void k_prep_fb(const float* __restrict__ q_enc,
                                                 const float* __restrict__ none_ent,
                                                 const float* __restrict__ W,
                                                 const float* __restrict__ bias,
                                                 const int* __restrict__ ranges,
                                                 u16* __restrict__ enc_hi, u16* __restrict__ enc_lo,
                                                 u16* __restrict__ w_hi, u16* __restrict__ w_lo,
                                                 float* __restrict__ ep_last,
                                                 float* __restrict__ co_att) {
    __shared__ float red4[4];
    int u = blockIdx.x, tid = threadIdx.x;
    if (u < M2_) d_encode(u, tid, q_enc, none_ent, W, bias, ranges, enc_hi, enc_lo, ep_last, red4);
    else if (u < M2_ + 1024) d_wsplit(u - M2_, tid, W, w_hi, w_lo);
    else { int lt = u - M2_ - 1024; d_zerotile(lt & 31, NBLK3_ + (lt >> 5), tid, co_att); }
}

__global__ __launch_bounds__(256, 2) void k_entproj_fb(const u16* __restrict__ A_hi, const u16* __restrict__ A_lo,
                                                       const u16* __restrict__ B_hi, const u16* __restrict__ B_lo,
                                                       const float* __restrict__ bias,
                                                       u16* __restrict__ ep_hi, u16* __restrict__ ep_lo) {
    __shared__ __attribute__((aligned(16))) P1s sm;
    d_entproj(blockIdx.x >> 3, blockIdx.x & 7, threadIdx.x, A_hi, A_lo, B_hi, B_lo, bias, ep_hi, ep_lo, &sm);
}

__global__ __launch_bounds__(256) void k_scores_fb(const float* __restrict__ q_enc,
                                                   const float* __restrict__ hint,
                                                   const u16* __restrict__ ep_hi, const u16* __restrict__ ep_lo,
                                                   const float* __restrict__ ep_last,
                                                   const int* __restrict__ qlen,
                                                   float* __restrict__ co_att,
                                                   float* __restrict__ partial) {
    __shared__ __attribute__((aligned(16))) P2s sm;
    d_scores(blockIdx.x & 31, blockIdx.x >> 5, threadIdx.x, q_enc, hint, ep_hi, ep_lo, ep_last,
             qlen, co_att, partial, &sm);
}

__global__ __launch_bounds__(256) void k_att_fb(const float* __restrict__ partial,
                                                float* __restrict__ att) {
    d_att(blockIdx.x, threadIdx.x, partial, att);
}

extern "C" void kernel_launch(void* const* d_in, const int* in_sizes, int n_in,
                              void* d_out, int out_size, void* d_ws, size_t ws_size,
                              hipStream_t stream) {
    const float* q_enc    = (const float*)d_in[0];
    const float* hint     = (const float*)d_in[1];
    const float* W        = (const float*)d_in[2];
    const float* bias     = (const float*)d_in[3];
    const float* none_ent = (const float*)d_in[4];
    const int*   qlen     = (const int*)d_in[5];
    const int*   ranges   = (const int*)d_in[6];

    float* att    = (float*)d_out;
    float* co_att = att + (size_t)B_ * E_;

    u16* enc_hi = (u16*)d_ws;
    u16* enc_lo = enc_hi + (size_t)M2P_ * 1024;
    u16* w_hi   = enc_lo + (size_t)M2P_ * 1024;
    u16* w_lo   = w_hi + (size_t)1024 * 1024;
    u16* ep_hi  = w_lo + (size_t)1024 * 1024;
    u16* ep_lo  = ep_hi + (size_t)M2P_ * 1024;
    float* ep_last = (float*)(ep_lo + (size_t)M2P_ * 1024);
    float* part    = ep_last + M2P_;

    void* args[] = {(void*)&q_enc, (void*)&hint, (void*)&W, (void*)&bias, (void*)&none_ent,
                    (void*)&qlen, (void*)&ranges,
                    (void*)&enc_hi, (void*)&enc_lo, (void*)&w_hi, (void*)&w_lo,
                    (void*)&ep_hi, (void*)&ep_lo, (void*)&ep_last,
                    (void*)&co_att, (void*)&part, (void*)&att};
    hipError_t err = hipLaunchCooperativeKernel((const void*)k_mega, dim3(NBLKS_), dim3(256),
                                                args, 0, stream);
    if (err != hipSuccess) {
        // fallback: equivalent 4-kernel pipeline (same device functions)
        k_prep_fb<<<NU0_, 256, 0, stream>>>(q_enc, none_ent, W, bias, ranges,
                                            enc_hi, enc_lo, w_hi, w_lo, ep_last, co_att);
        k_entproj_fb<<<208, 256, 0, stream>>>(enc_hi, enc_lo, w_hi, w_lo, bias, ep_hi, ep_lo);
        k_scores_fb<<<B_ * NBLK3_, 256, 0, stream>>>(q_enc, hint, ep_hi, ep_lo, ep_last, qlen,
                                                     co_att, part);
        k_att_fb<<<B_, 256, 0, stream>>>(part, att);
    }
}

// Round 8
// 85.443 us; speedup vs baseline: 3.4570x; 3.4570x over previous
//
#include <hip/hip_runtime.h>
#include <hip/hip_bf16.h>

typedef unsigned short u16;
typedef __attribute__((ext_vector_type(8))) short short8;
typedef __attribute__((ext_vector_type(4))) float f32x4;

#define B_ 32
#define L_ 1024
#define D_ 1024
#define E_ 100
#define E1_ 101
#define M2_ (B_ * E1_)     // 3232 entity rows (incl. none-entity)
#define M2P_ 3328          // padded to 26*128 for MFMA tiles
#define QBLK_ 16           // rows per scores block (smaller -> 416 blocks -> >1/CU)
#define NT3_ 13            // ceil(Q_MAX=200 / 16) tiles that can contain valid rows
#define ZROW0_ (NT3_ * QBLK_)  // 208: first always-masked row

#define MFMA16(a, b, c) __builtin_amdgcn_mfma_f32_16x16x32_bf16((a), (b), (c), 0, 0, 0)

__device__ __forceinline__ void split2(float x, u16& h, u16& l) {
    __hip_bfloat16 bh = __float2bfloat16(x);          // RN
    float r = x - __bfloat162float(bh);
    __hip_bfloat16 bl = __float2bfloat16(r);
    h = __builtin_bit_cast(u16, bh);
    l = __builtin_bit_cast(u16, bl);
}

// async global->LDS, 16B per lane; LDS dest = wave-uniform base + lane*16
__device__ __forceinline__ void gload16(const void* g, void* l) {
    __builtin_amdgcn_global_load_lds(
        (const __attribute__((address_space(1))) unsigned int*)g,
        (__attribute__((address_space(3))) unsigned int*)l, 16, 0, 0);
}

// ---------------- K0: zero co_att rows >= ZROW0_ (always masked)
__global__ __launch_bounds__(256) void k_zerofill(float* __restrict__ co_att) {
    int b = blockIdx.y;
    float4* base = (float4*)&co_att[((size_t)b * L_ + ZROW0_) * E1_];
    const int n4 = (L_ - ZROW0_) * E1_ / 4;   // 816*101/4 = 20604
    float4 z = make_float4(0.f, 0.f, 0.f, 0.f);
    for (int i = blockIdx.x * 256 + threadIdx.x; i < n4; i += gridDim.x * 256)
        base[i] = z;
}

// ---------------- K1: segment-sum -> enc hi/lo bf16 split; fused last column
__global__ __launch_bounds__(256) void k_encode(const float* __restrict__ q_enc,
                                                const float* __restrict__ none_ent,
                                                const float* __restrict__ W,
                                                const float* __restrict__ bias,
                                                const int* __restrict__ ranges,
                                                u16* __restrict__ enc_hi, u16* __restrict__ enc_lo,
                                                float* __restrict__ ep_last) {
    __shared__ float red4[4];
    int be = blockIdx.x;
    int b = be / E1_, e = be - b * E1_;
    int t = threadIdx.x, c = t * 4;
    float4 acc;
    if (e == E_) {
        acc = *(const float4*)&none_ent[c];
    } else {
        acc = make_float4(0.f, 0.f, 0.f, 0.f);
        int r0 = ranges[(b * E_ + e) * 2 + 0];
        int r1 = ranges[(b * E_ + e) * 2 + 1];
        for (int l = r0 + 1; l < r1; ++l) {
            float4 v = *(const float4*)&q_enc[((size_t)b * L_ + l) * D_ + c];
            acc.x += v.x; acc.y += v.y; acc.z += v.z; acc.w += v.w;
        }
    }
    union { u16 u[4]; float2 f; } ph, pl;
    split2(acc.x, ph.u[0], pl.u[0]); split2(acc.y, ph.u[1], pl.u[1]);
    split2(acc.z, ph.u[2], pl.u[2]); split2(acc.w, ph.u[3], pl.u[3]);
    *(float2*)&enc_hi[(size_t)be * 1024 + c] = ph.f;
    *(float2*)&enc_lo[(size_t)be * 1024 + c] = pl.f;
    const float* w1k = W + (size_t)1024 * 1024;
    float4 wv = *(const float4*)&w1k[c];
    float s = acc.x * wv.x + acc.y * wv.y + acc.z * wv.z + acc.w * wv.w;
    #pragma unroll
    for (int off = 32; off; off >>= 1) s += __shfl_down(s, off);
    if ((t & 63) == 0) red4[t >> 6] = s;
    __syncthreads();
    if (t == 0) ep_last[be] = red4[0] + red4[1] + red4[2] + red4[3] + bias[1024];
}

// ---------------- K2: W rows 0..1023 -> bf16 hi/lo
__global__ __launch_bounds__(256) void k_wsplit(const float* __restrict__ W,
                                                u16* __restrict__ w_hi, u16* __restrict__ w_lo) {
    int r = blockIdx.x, c = threadIdx.x * 4;
    float4 v = *(const float4*)&W[(size_t)r * 1024 + c];
    union { u16 u[4]; float2 f; } ph, pl;
    split2(v.x, ph.u[0], pl.u[0]); split2(v.y, ph.u[1], pl.u[1]);
    split2(v.z, ph.u[2], pl.u[2]); split2(v.w, ph.u[3], pl.u[3]);
    *(float2*)&w_hi[(size_t)r * 1024 + c] = ph.f;
    *(float2*)&w_lo[(size_t)r * 1024 + c] = pl.f;
}

// ---------------- K3: ep = enc . W^T + bias, 3-term bf16 MFMA
// 128x64 tile -> grid (16,26)=416 blocks, LDS 48KB (3 blocks/CU capable).
// 4 waves (2x2): wave covers 64 rows x 32 cols = 4x2 frags.
__global__ __launch_bounds__(256, 2) void k_entproj(const u16* __restrict__ A_hi, const u16* __restrict__ A_lo,
                                                    const u16* __restrict__ B_hi, const u16* __restrict__ B_lo,
                                                    const float* __restrict__ bias,
                                                    u16* __restrict__ ep_hi, u16* __restrict__ ep_lo) {
    __shared__ __attribute__((aligned(16))) u16 Ah[128 * 64], Al[128 * 64], Bh[64 * 64], Bl[64 * 64];
    int tid = threadIdx.x;
    int m0 = blockIdx.y * 128, n0 = blockIdx.x * 64;
    int w = tid >> 6, lane = tid & 63, lr = lane & 15, lg = lane >> 4;
    int wr = w >> 1, wc = w & 1;
    f32x4 zero = {0.f, 0.f, 0.f, 0.f};
    f32x4 acc[4][2];
    #pragma unroll
    for (int i = 0; i < 4; ++i) { acc[i][0] = zero; acc[i][1] = zero; }
    for (int k0 = 0; k0 < 1024; k0 += 64) {
        // A: 1024 slots (128 rows x 8 sgroups), 4 per lane
        #pragma unroll
        for (int j = 0; j < 4; ++j) {
            int slot = w * 256 + j * 64 + lane;
            int r = slot >> 3, s = slot & 7;
            int g = (s ^ (r & 7)) << 3;
            size_t ga = (size_t)(m0 + r) * 1024 + k0 + g;
            int ld = (w * 256 + j * 64) * 8;
            gload16(&A_hi[ga], &Ah[ld]);
            gload16(&A_lo[ga], &Al[ld]);
        }
        // B: 512 slots (64 rows x 8 sgroups), 2 per lane
        #pragma unroll
        for (int j = 0; j < 2; ++j) {
            int slot = w * 128 + j * 64 + lane;
            int r = slot >> 3, s = slot & 7;
            int g = (s ^ (r & 7)) << 3;
            size_t gb = (size_t)(n0 + r) * 1024 + k0 + g;
            int ld = (w * 128 + j * 64) * 8;
            gload16(&B_hi[gb], &Bh[ld]);
            gload16(&B_lo[gb], &Bl[ld]);
        }
        __syncthreads();
        #pragma unroll
        for (int half = 0; half < 2; ++half) {
            int sk = half * 4 + lg;
            short8 a_h[4], a_l[4], b_h[2], b_l[2];
            #pragma unroll
            for (int mf = 0; mf < 4; ++mf) {
                int R = wr * 64 + mf * 16 + lr;
                int ad = R * 64 + ((sk ^ (R & 7)) << 3);
                a_h[mf] = __builtin_bit_cast(short8, *(const float4*)&Ah[ad]);
                a_l[mf] = __builtin_bit_cast(short8, *(const float4*)&Al[ad]);
            }
            #pragma unroll
            for (int nf = 0; nf < 2; ++nf) {
                int R = wc * 32 + nf * 16 + lr;
                int ad = R * 64 + ((sk ^ (R & 7)) << 3);
                b_h[nf] = __builtin_bit_cast(short8, *(const float4*)&Bh[ad]);
                b_l[nf] = __builtin_bit_cast(short8, *(const float4*)&Bl[ad]);
            }
            #pragma unroll
            for (int mf = 0; mf < 4; ++mf)
                #pragma unroll
                for (int nf = 0; nf < 2; ++nf) {
                    acc[mf][nf] = MFMA16(a_h[mf], b_h[nf], acc[mf][nf]);
                    acc[mf][nf] = MFMA16(a_h[mf], b_l[nf], acc[mf][nf]);
                    acc[mf][nf] = MFMA16(a_l[mf], b_h[nf], acc[mf][nf]);
                }
        }
        __syncthreads();
    }
    #pragma unroll
    for (int mf = 0; mf < 4; ++mf)
        #pragma unroll
        for (int nf = 0; nf < 2; ++nf)
            #pragma unroll
            for (int reg = 0; reg < 4; ++reg) {
                int m = m0 + wr * 64 + mf * 16 + lg * 4 + reg;
                if (m < M2_) {
                    int n = n0 + wc * 32 + nf * 16 + lr;
                    float v = acc[mf][nf][reg] + bias[n];
                    u16 h, l;
                    split2(v, h, l);
                    ep_hi[(size_t)m * 1024 + n] = h;
                    ep_lo[(size_t)m * 1024 + n] = l;
                }
            }
}

// ---------------- K4: scores (MFMA) + fused softmax + co_att writes
// QBLK=16 -> grid (13,32)=416 blocks, LDS ~44KB (3 blocks/CU capable).
// 4 waves: wave w computes nf frags {2w, 2w+1} (wave3: {6}).
__global__ __launch_bounds__(256, 3) void k_scores(const float* __restrict__ q_enc,
                                                   const float* __restrict__ hint,
                                                   const u16* __restrict__ ep_hi, const u16* __restrict__ ep_lo,
                                                   const float* __restrict__ ep_last,
                                                   const int* __restrict__ qlen,
                                                   float* __restrict__ co_att,
                                                   float* __restrict__ partial) {
    __shared__ __attribute__((aligned(16))) u16 Ah[16 * 64], Al[16 * 64], Bh[128 * 64], Bl[128 * 64];
    __shared__ float Ss[16 * 113];
    __shared__ float red[QBLK_][16];
    int b = blockIdx.y, mt = blockIdx.x, l0 = mt * QBLK_;
    int tid = threadIdx.x;
    int qn = qlen[b];
    if (l0 >= qn) {
        // masked tile: zero co_att rows + zero partial
        float* base = &co_att[((size_t)b * L_ + l0) * E1_];
        float4 z = make_float4(0.f, 0.f, 0.f, 0.f);
        for (int i = tid; i < QBLK_ * E1_ / 4; i += 256)
            *(float4*)&base[i * 4] = z;
        for (int e = tid; e < E1_; e += 256)
            partial[((size_t)b * NT3_ + mt) * E1_ + e] = 0.f;
        return;
    }
    int w = tid >> 6, lane = tid & 63, lr = lane & 15, lg = lane >> 4;
    int nb = w * 2, nc = (w == 3) ? 1 : 2;    // frags nb..nb+nc-1
    int sb = w * 256;
    f32x4 zero = {0.f, 0.f, 0.f, 0.f};
    f32x4 acc[2] = {zero, zero};
    for (int k0 = 0; k0 < 1024; k0 += 64) {
        {   // B: 128 rows x 64 k via gload_lds (rows >100 finite garbage, masked later)
            #pragma unroll
            for (int j = 0; j < 4; ++j) {
                int slot = sb + j * 64 + lane;
                int r = slot >> 3, s = slot & 7;
                int g = (s ^ (r & 7)) << 3;
                size_t gb = ((size_t)b * E1_ + r) * 1024 + k0 + g;
                int ld = (sb + j * 64) * 8;
                gload16(&ep_hi[gb], &Bh[ld]);
                gload16(&ep_lo[gb], &Bl[ld]);
            }
        }
        if (tid < 128) {  // A: 16 rows x 64 k, split fp32 -> hi/lo on the fly
            int r = tid >> 3, s = tid & 7;
            const float* src = &q_enc[((size_t)b * L_ + l0 + r) * D_ + k0 + s * 8];
            float4 x0 = *(const float4*)src, x1 = *(const float4*)(src + 4);
            float xs[8] = {x0.x, x0.y, x0.z, x0.w, x1.x, x1.y, x1.z, x1.w};
            short8 hv, lv;
            #pragma unroll
            for (int j = 0; j < 8; ++j) {
                u16 hh, ll;
                split2(xs[j], hh, ll);
                hv[j] = (short)hh; lv[j] = (short)ll;
            }
            int dst = r * 64 + ((s ^ (r & 7)) << 3);
            *(float4*)&Ah[dst] = __builtin_bit_cast(float4, hv);
            *(float4*)&Al[dst] = __builtin_bit_cast(float4, lv);
        }
        __syncthreads();
        #pragma unroll
        for (int ks = 0; ks < 2; ++ks) {
            int sk = ks * 4 + lg;
            int adA = lr * 64 + ((sk ^ (lr & 7)) << 3);
            short8 ah = __builtin_bit_cast(short8, *(const float4*)&Ah[adA]);
            short8 al = __builtin_bit_cast(short8, *(const float4*)&Al[adA]);
            #pragma unroll
            for (int nf = 0; nf < 2; ++nf) {
                if (nf < nc) {
                    int rB = (nb + nf) * 16 + lr;
                    int adB = rB * 64 + ((sk ^ (rB & 7)) << 3);
                    short8 bh = __builtin_bit_cast(short8, *(const float4*)&Bh[adB]);
                    short8 bl = __builtin_bit_cast(short8, *(const float4*)&Bl[adB]);
                    acc[nf] = MFMA16(ah, bh, acc[nf]);
                    acc[nf] = MFMA16(ah, bl, acc[nf]);
                    acc[nf] = MFMA16(al, bh, acc[nf]);
                }
            }
        }
        __syncthreads();
    }
    // dump score frags: row = lg*4 + reg, col = (nb+nf)*16 + lr
    #pragma unroll
    for (int nf = 0; nf < 2; ++nf)
        if (nf < nc) {
            #pragma unroll
            for (int reg = 0; reg < 4; ++reg)
                Ss[(lg * 4 + reg) * 113 + (nb + nf) * 16 + lr] = acc[nf][reg];
        }
    __syncthreads();
    // ---- softmax over 101 entities per row: 16 rows x 16 entity-groups
    int l = tid & 15, eg = tid >> 4;
    float h = hint[(size_t)b * L_ + l0 + l];
    float sc[7];
    #pragma unroll
    for (int j = 0; j < 7; ++j) {
        int e = eg + 16 * j;
        sc[j] = (e < E1_) ? (Ss[l * 113 + e] + h * ep_last[b * E1_ + e]) : -3.4e38f;
    }
    float mloc = -3.4e38f;
    #pragma unroll
    for (int j = 0; j < 7; ++j) mloc = fmaxf(mloc, sc[j]);
    red[l][eg] = mloc;
    __syncthreads();
    float m = red[l][0];
    #pragma unroll
    for (int k = 1; k < 16; ++k) m = fmaxf(m, red[l][k]);
    __syncthreads();
    float p[7];
    float sloc = 0.f;
    #pragma unroll
    for (int j = 0; j < 7; ++j) {
        p[j] = 0.f;
        if (eg + 16 * j < E1_) { p[j] = __expf(sc[j] - m); sloc += p[j]; }
    }
    red[l][eg] = sloc;
    __syncthreads();
    float ssum = 0.f;
    #pragma unroll
    for (int k = 0; k < 16; ++k) ssum += red[l][k];
    float inv = 1.f / ssum;
    bool valid = (l0 + l) < qn;
    float maskv = valid ? inv : 0.f;
    float* row = &co_att[((size_t)b * L_ + l0 + l) * E1_];
    #pragma unroll
    for (int j = 0; j < 7; ++j) {
        int e = eg + 16 * j;
        if (e < E1_) row[e] = p[j] * maskv;
    }
    // partial att: sum over this tile's valid rows (16-lane group reduce over l)
    #pragma unroll
    for (int j = 0; j < 7; ++j) {
        int e = eg + 16 * j;
        float v = (e < E1_) ? p[j] * maskv : 0.f;
        v += __shfl_xor(v, 1);  v += __shfl_xor(v, 2);
        v += __shfl_xor(v, 4);  v += __shfl_xor(v, 8);
        if ((tid & 15) == 0 && e < E1_)
            partial[((size_t)b * NT3_ + mt) * E1_ + e] = v;
    }
}

// ---------------- K5: att[b,e] = min(sum of partials, 1)
__global__ __launch_bounds__(256) void k_final(const float* __restrict__ partial,
                                               float* __restrict__ att) {
    int i = blockIdx.x * 256 + threadIdx.x;
    if (i >= B_ * E_) return;
    int b = i / E_, e = i % E_;
    float s = 0.f;
    #pragma unroll
    for (int k = 0; k < NT3_; ++k) s += partial[((size_t)b * NT3_ + k) * E1_ + e];
    att[i] = fminf(s, 1.f);
}

extern "C" void kernel_launch(void* const* d_in, const int* in_sizes, int n_in,
                              void* d_out, int out_size, void* d_ws, size_t ws_size,
                              hipStream_t stream) {
    const float* q_enc    = (const float*)d_in[0];
    const float* hint     = (const float*)d_in[1];
    const float* W        = (const float*)d_in[2];
    const float* bias     = (const float*)d_in[3];
    const float* none_ent = (const float*)d_in[4];
    const int*   qlen     = (const int*)d_in[5];
    const int*   ranges   = (const int*)d_in[6];

    float* att    = (float*)d_out;
    float* co_att = att + (size_t)B_ * E_;

    u16* enc_hi = (u16*)d_ws;
    u16* enc_lo = enc_hi + (size_t)M2P_ * 1024;
    u16* w_hi   = enc_lo + (size_t)M2P_ * 1024;
    u16* w_lo   = w_hi + (size_t)1024 * 1024;
    u16* ep_hi  = w_lo + (size_t)1024 * 1024;
    u16* ep_lo  = ep_hi + (size_t)M2P_ * 1024;
    float* ep_last = (float*)(ep_lo + (size_t)M2P_ * 1024);
    float* part    = ep_last + M2P_;

    k_zerofill<<<dim3(20, B_), 256, 0, stream>>>(co_att);
    k_encode<<<M2_, 256, 0, stream>>>(q_enc, none_ent, W, bias, ranges, enc_hi, enc_lo, ep_last);
    k_wsplit<<<1024, 256, 0, stream>>>(W, w_hi, w_lo);
    k_entproj<<<dim3(16, 26), 256, 0, stream>>>(enc_hi, enc_lo, w_hi, w_lo, bias, ep_hi, ep_lo);
    k_scores<<<dim3(NT3_, B_), 256, 0, stream>>>(q_enc, hint, ep_hi, ep_lo, ep_last, qlen, co_att, part);
    k_final<<<13, 256, 0, stream>>>(part, att);
}

// Round 9
// 80.348 us; speedup vs baseline: 3.6762x; 1.0634x over previous
//
#include <hip/hip_runtime.h>
#include <hip/hip_bf16.h>

typedef unsigned short u16;
typedef __attribute__((ext_vector_type(8))) short short8;
typedef __attribute__((ext_vector_type(4))) float f32x4;

#define B_ 32
#define L_ 1024
#define D_ 1024
#define E_ 100
#define E1_ 101
#define M2_ (B_ * E1_)     // 3232 entity rows (incl. none-entity)
#define M2P_ 3328          // padded to 52*64 for MFMA tiles
#define QBLK_ 16           // rows per scores block
#define NT3_ 13            // ceil(Q_MAX=200 / 16) tiles that can contain valid rows
#define ZROW0_ (NT3_ * QBLK_)  // 208: first always-masked row
#define NZF_ 640               // zerofill blocks (20 per batch)
#define NPREP_ (M2_ + 1024 + NZF_)

#define MFMA16(a, b, c) __builtin_amdgcn_mfma_f32_16x16x32_bf16((a), (b), (c), 0, 0, 0)

__device__ __forceinline__ void split2(float x, u16& h, u16& l) {
    __hip_bfloat16 bh = __float2bfloat16(x);          // RN
    float r = x - __bfloat162float(bh);
    __hip_bfloat16 bl = __float2bfloat16(r);
    h = __builtin_bit_cast(u16, bh);
    l = __builtin_bit_cast(u16, bl);
}

// async global->LDS, 16B per lane; LDS dest = wave-uniform base + lane*16
__device__ __forceinline__ void gload16(const void* g, void* l) {
    __builtin_amdgcn_global_load_lds(
        (const __attribute__((address_space(1))) unsigned int*)g,
        (__attribute__((address_space(3))) unsigned int*)l, 16, 0, 0);
}

// ---------------- K1: flat fusion of [encode | wsplit | zerofill] (all independent)
__global__ __launch_bounds__(256) void k_prep(const float* __restrict__ q_enc,
                                              const float* __restrict__ none_ent,
                                              const float* __restrict__ W,
                                              const float* __restrict__ bias,
                                              const int* __restrict__ ranges,
                                              u16* __restrict__ enc_hi, u16* __restrict__ enc_lo,
                                              u16* __restrict__ w_hi, u16* __restrict__ w_lo,
                                              float* __restrict__ ep_last,
                                              float* __restrict__ co_att) {
    __shared__ float red4[4];
    int u = blockIdx.x;
    int t = threadIdx.x, c = t * 4;
    if (u < M2_) {
        // ---- encode unit: one (b, e) entity row
        int b = u / E1_, e = u - b * E1_;
        float4 acc;
        if (e == E_) {
            acc = *(const float4*)&none_ent[c];
        } else {
            acc = make_float4(0.f, 0.f, 0.f, 0.f);
            int r0 = ranges[(b * E_ + e) * 2 + 0];
            int r1 = ranges[(b * E_ + e) * 2 + 1];
            for (int l = r0 + 1; l < r1; ++l) {
                float4 v = *(const float4*)&q_enc[((size_t)b * L_ + l) * D_ + c];
                acc.x += v.x; acc.y += v.y; acc.z += v.z; acc.w += v.w;
            }
        }
        union { u16 uu[4]; float2 f; } ph, pl;
        split2(acc.x, ph.uu[0], pl.uu[0]); split2(acc.y, ph.uu[1], pl.uu[1]);
        split2(acc.z, ph.uu[2], pl.uu[2]); split2(acc.w, ph.uu[3], pl.uu[3]);
        *(float2*)&enc_hi[(size_t)u * 1024 + c] = ph.f;
        *(float2*)&enc_lo[(size_t)u * 1024 + c] = pl.f;
        const float* w1k = W + (size_t)1024 * 1024;
        float4 wv = *(const float4*)&w1k[c];
        float s = acc.x * wv.x + acc.y * wv.y + acc.z * wv.z + acc.w * wv.w;
        #pragma unroll
        for (int off = 32; off; off >>= 1) s += __shfl_down(s, off);
        if ((t & 63) == 0) red4[t >> 6] = s;
        __syncthreads();
        if (t == 0) ep_last[u] = red4[0] + red4[1] + red4[2] + red4[3] + bias[1024];
    } else if (u < M2_ + 1024) {
        // ---- wsplit unit: one W row
        int r = u - M2_;
        float4 v = *(const float4*)&W[(size_t)r * 1024 + c];
        union { u16 uu[4]; float2 f; } ph, pl;
        split2(v.x, ph.uu[0], pl.uu[0]); split2(v.y, ph.uu[1], pl.uu[1]);
        split2(v.z, ph.uu[2], pl.uu[2]); split2(v.w, ph.uu[3], pl.uu[3]);
        *(float2*)&w_hi[(size_t)r * 1024 + c] = ph.f;
        *(float2*)&w_lo[(size_t)r * 1024 + c] = pl.f;
    } else {
        // ---- zerofill unit: 1/20th of one batch's always-masked co_att rows
        int zu = u - M2_ - 1024;          // 0..639
        int b = zu / 20, part = zu % 20;
        float4* base = (float4*)&co_att[((size_t)b * L_ + ZROW0_) * E1_];
        const int n4 = (L_ - ZROW0_) * E1_ / 4;   // 816*101/4 = 20604
        float4 z = make_float4(0.f, 0.f, 0.f, 0.f);
        for (int i = part * 256 + t; i < n4; i += 20 * 256)
            base[i] = z;
    }
}

// ---------------- K2: ep = enc . W^T + bias, 3-term bf16 MFMA
// 64x64 tile -> grid (16,52) = 832 blocks (~3.25/CU, balanced tail), LDS 32KB.
// 4 waves (2x2): wave covers 32 rows x 32 cols = 2x2 frags of 16x16x32.
__global__ __launch_bounds__(256, 2) void k_entproj(const u16* __restrict__ A_hi, const u16* __restrict__ A_lo,
                                                    const u16* __restrict__ B_hi, const u16* __restrict__ B_lo,
                                                    const float* __restrict__ bias,
                                                    u16* __restrict__ ep_hi, u16* __restrict__ ep_lo) {
    __shared__ __attribute__((aligned(16))) u16 Ah[64 * 64], Al[64 * 64], Bh[64 * 64], Bl[64 * 64];
    int tid = threadIdx.x;
    int m0 = blockIdx.y * 64, n0 = blockIdx.x * 64;
    int w = tid >> 6, lane = tid & 63, lr = lane & 15, lg = lane >> 4;
    int wr = w >> 1, wc = w & 1;
    f32x4 zero = {0.f, 0.f, 0.f, 0.f};
    f32x4 acc[2][2] = {{zero, zero}, {zero, zero}};
    for (int k0 = 0; k0 < 1024; k0 += 64) {
        // 512 slots per array (64 rows x 8 sgroups); per wave 128 slots (2 j-iters)
        #pragma unroll
        for (int j = 0; j < 2; ++j) {
            int slot = w * 128 + j * 64 + lane;   // slot = r*8 + s
            int r = slot >> 3, s = slot & 7;
            int g = (s ^ (r & 7)) << 3;           // pre-swizzled source column group
            size_t ga = (size_t)(m0 + r) * 1024 + k0 + g;
            size_t gb = (size_t)(n0 + r) * 1024 + k0 + g;
            int ld = (w * 128 + j * 64) * 8;      // wave-uniform LDS base (u16 idx)
            gload16(&A_hi[ga], &Ah[ld]);
            gload16(&A_lo[ga], &Al[ld]);
            gload16(&B_hi[gb], &Bh[ld]);
            gload16(&B_lo[gb], &Bl[ld]);
        }
        __syncthreads();
        #pragma unroll
        for (int half = 0; half < 2; ++half) {
            int sk = half * 4 + lg;
            short8 a_h[2], a_l[2], b_h[2], b_l[2];
            #pragma unroll
            for (int mf = 0; mf < 2; ++mf) {
                int R = wr * 32 + mf * 16 + lr;
                int ad = R * 64 + ((sk ^ (R & 7)) << 3);
                a_h[mf] = __builtin_bit_cast(short8, *(const float4*)&Ah[ad]);
                a_l[mf] = __builtin_bit_cast(short8, *(const float4*)&Al[ad]);
            }
            #pragma unroll
            for (int nf = 0; nf < 2; ++nf) {
                int R = wc * 32 + nf * 16 + lr;
                int ad = R * 64 + ((sk ^ (R & 7)) << 3);
                b_h[nf] = __builtin_bit_cast(short8, *(const float4*)&Bh[ad]);
                b_l[nf] = __builtin_bit_cast(short8, *(const float4*)&Bl[ad]);
            }
            #pragma unroll
            for (int mf = 0; mf < 2; ++mf)
                #pragma unroll
                for (int nf = 0; nf < 2; ++nf) {
                    acc[mf][nf] = MFMA16(a_h[mf], b_h[nf], acc[mf][nf]);
                    acc[mf][nf] = MFMA16(a_h[mf], b_l[nf], acc[mf][nf]);
                    acc[mf][nf] = MFMA16(a_l[mf], b_h[nf], acc[mf][nf]);
                }
        }
        __syncthreads();
    }
    #pragma unroll
    for (int mf = 0; mf < 2; ++mf)
        #pragma unroll
        for (int nf = 0; nf < 2; ++nf)
            #pragma unroll
            for (int reg = 0; reg < 4; ++reg) {
                int m = m0 + wr * 32 + mf * 16 + lg * 4 + reg;
                if (m < M2_) {
                    int n = n0 + wc * 32 + nf * 16 + lr;
                    float v = acc[mf][nf][reg] + bias[n];
                    u16 h, l;
                    split2(v, h, l);
                    ep_hi[(size_t)m * 1024 + n] = h;
                    ep_lo[(size_t)m * 1024 + n] = l;
                }
            }
}

// ---------------- K3: scores (MFMA) + fused softmax + co_att writes
// QBLK=16 -> grid (13,32)=416 blocks, LDS ~44KB (3 blocks/CU).
__global__ __launch_bounds__(256, 3) void k_scores(const float* __restrict__ q_enc,
                                                   const float* __restrict__ hint,
                                                   const u16* __restrict__ ep_hi, const u16* __restrict__ ep_lo,
                                                   const float* __restrict__ ep_last,
                                                   const int* __restrict__ qlen,
                                                   float* __restrict__ co_att,
                                                   float* __restrict__ partial) {
    __shared__ __attribute__((aligned(16))) u16 Ah[16 * 64], Al[16 * 64], Bh[128 * 64], Bl[128 * 64];
    __shared__ float Ss[16 * 113];
    __shared__ float red[QBLK_][16];
    int b = blockIdx.y, mt = blockIdx.x, l0 = mt * QBLK_;
    int tid = threadIdx.x;
    int qn = qlen[b];
    if (l0 >= qn) {
        // masked tile: zero co_att rows + zero partial
        float* base = &co_att[((size_t)b * L_ + l0) * E1_];
        float4 z = make_float4(0.f, 0.f, 0.f, 0.f);
        for (int i = tid; i < QBLK_ * E1_ / 4; i += 256)
            *(float4*)&base[i * 4] = z;
        for (int e = tid; e < E1_; e += 256)
            partial[((size_t)b * NT3_ + mt) * E1_ + e] = 0.f;
        return;
    }
    int w = tid >> 6, lane = tid & 63, lr = lane & 15, lg = lane >> 4;
    int nb = w * 2, nc = (w == 3) ? 1 : 2;    // frags nb..nb+nc-1
    int sb = w * 256;
    f32x4 zero = {0.f, 0.f, 0.f, 0.f};
    f32x4 acc[2] = {zero, zero};
    for (int k0 = 0; k0 < 1024; k0 += 64) {
        {   // B: 128 rows x 64 k via gload_lds (rows >100 finite garbage, masked later)
            #pragma unroll
            for (int j = 0; j < 4; ++j) {
                int slot = sb + j * 64 + lane;
                int r = slot >> 3, s = slot & 7;
                int g = (s ^ (r & 7)) << 3;
                size_t gb = ((size_t)b * E1_ + r) * 1024 + k0 + g;
                int ld = (sb + j * 64) * 8;
                gload16(&ep_hi[gb], &Bh[ld]);
                gload16(&ep_lo[gb], &Bl[ld]);
            }
        }
        if (tid < 128) {  // A: 16 rows x 64 k, split fp32 -> hi/lo on the fly
            int r = tid >> 3, s = tid & 7;
            const float* src = &q_enc[((size_t)b * L_ + l0 + r) * D_ + k0 + s * 8];
            float4 x0 = *(const float4*)src, x1 = *(const float4*)(src + 4);
            float xs[8] = {x0.x, x0.y, x0.z, x0.w, x1.x, x1.y, x1.z, x1.w};
            short8 hv, lv;
            #pragma unroll
            for (int j = 0; j < 8; ++j) {
                u16 hh, ll;
                split2(xs[j], hh, ll);
                hv[j] = (short)hh; lv[j] = (short)ll;
            }
            int dst = r * 64 + ((s ^ (r & 7)) << 3);
            *(float4*)&Ah[dst] = __builtin_bit_cast(float4, hv);
            *(float4*)&Al[dst] = __builtin_bit_cast(float4, lv);
        }
        __syncthreads();
        #pragma unroll
        for (int ks = 0; ks < 2; ++ks) {
            int sk = ks * 4 + lg;
            int adA = lr * 64 + ((sk ^ (lr & 7)) << 3);
            short8 ah = __builtin_bit_cast(short8, *(const float4*)&Ah[adA]);
            short8 al = __builtin_bit_cast(short8, *(const float4*)&Al[adA]);
            #pragma unroll
            for (int nf = 0; nf < 2; ++nf) {
                if (nf < nc) {
                    int rB = (nb + nf) * 16 + lr;
                    int adB = rB * 64 + ((sk ^ (rB & 7)) << 3);
                    short8 bh = __builtin_bit_cast(short8, *(const float4*)&Bh[adB]);
                    short8 bl = __builtin_bit_cast(short8, *(const float4*)&Bl[adB]);
                    acc[nf] = MFMA16(ah, bh, acc[nf]);
                    acc[nf] = MFMA16(ah, bl, acc[nf]);
                    acc[nf] = MFMA16(al, bh, acc[nf]);
                }
            }
        }
        __syncthreads();
    }
    // dump score frags: row = lg*4 + reg, col = (nb+nf)*16 + lr
    #pragma unroll
    for (int nf = 0; nf < 2; ++nf)
        if (nf < nc) {
            #pragma unroll
            for (int reg = 0; reg < 4; ++reg)
                Ss[(lg * 4 + reg) * 113 + (nb + nf) * 16 + lr] = acc[nf][reg];
        }
    __syncthreads();
    // ---- softmax over 101 entities per row: 16 rows x 16 entity-groups
    int l = tid & 15, eg = tid >> 4;
    float h = hint[(size_t)b * L_ + l0 + l];
    float sc[7];
    #pragma unroll
    for (int j = 0; j < 7; ++j) {
        int e = eg + 16 * j;
        sc[j] = (e < E1_) ? (Ss[l * 113 + e] + h * ep_last[b * E1_ + e]) : -3.4e38f;
    }
    float mloc = -3.4e38f;
    #pragma unroll
    for (int j = 0; j < 7; ++j) mloc = fmaxf(mloc, sc[j]);
    red[l][eg] = mloc;
    __syncthreads();
    float m = red[l][0];
    #pragma unroll
    for (int k = 1; k < 16; ++k) m = fmaxf(m, red[l][k]);
    __syncthreads();
    float p[7];
    float sloc = 0.f;
    #pragma unroll
    for (int j = 0; j < 7; ++j) {
        p[j] = 0.f;
        if (eg + 16 * j < E1_) { p[j] = __expf(sc[j] - m); sloc += p[j]; }
    }
    red[l][eg] = sloc;
    __syncthreads();
    float ssum = 0.f;
    #pragma unroll
    for (int k = 0; k < 16; ++k) ssum += red[l][k];
    float inv = 1.f / ssum;
    bool valid = (l0 + l) < qn;
    float maskv = valid ? inv : 0.f;
    float* row = &co_att[((size_t)b * L_ + l0 + l) * E1_];
    #pragma unroll
    for (int j = 0; j < 7; ++j) {
        int e = eg + 16 * j;
        if (e < E1_) row[e] = p[j] * maskv;
    }
    // partial att: sum over this tile's valid rows (16-lane group reduce over l)
    #pragma unroll
    for (int j = 0; j < 7; ++j) {
        int e = eg + 16 * j;
        float v = (e < E1_) ? p[j] * maskv : 0.f;
        v += __shfl_xor(v, 1);  v += __shfl_xor(v, 2);
        v += __shfl_xor(v, 4);  v += __shfl_xor(v, 8);
        if ((tid & 15) == 0 && e < E1_)
            partial[((size_t)b * NT3_ + mt) * E1_ + e] = v;
    }
}

// ---------------- K4: att[b,e] = min(sum of partials, 1)
__global__ __launch_bounds__(256) void k_final(const float* __restrict__ partial,
                                               float* __restrict__ att) {
    int i = blockIdx.x * 256 + threadIdx.x;
    if (i >= B_ * E_) return;
    int b = i / E_, e = i % E_;
    float s = 0.f;
    #pragma unroll
    for (int k = 0; k < NT3_; ++k) s += partial[((size_t)b * NT3_ + k) * E1_ + e];
    att[i] = fminf(s, 1.f);
}

extern "C" void kernel_launch(void* const* d_in, const int* in_sizes, int n_in,
                              void* d_out, int out_size, void* d_ws, size_t ws_size,
                              hipStream_t stream) {
    const float* q_enc    = (const float*)d_in[0];
    const float* hint     = (const float*)d_in[1];
    const float* W        = (const float*)d_in[2];
    const float* bias     = (const float*)d_in[3];
    const float* none_ent = (const float*)d_in[4];
    const int*   qlen     = (const int*)d_in[5];
    const int*   ranges   = (const int*)d_in[6];

    float* att    = (float*)d_out;
    float* co_att = att + (size_t)B_ * E_;

    u16* enc_hi = (u16*)d_ws;
    u16* enc_lo = enc_hi + (size_t)M2P_ * 1024;
    u16* w_hi   = enc_lo + (size_t)M2P_ * 1024;
    u16* w_lo   = w_hi + (size_t)1024 * 1024;
    u16* ep_hi  = w_lo + (size_t)1024 * 1024;
    u16* ep_lo  = ep_hi + (size_t)M2P_ * 1024;
    float* ep_last = (float*)(ep_lo + (size_t)M2P_ * 1024);
    float* part    = ep_last + M2P_;

    k_prep<<<NPREP_, 256, 0, stream>>>(q_enc, none_ent, W, bias, ranges,
                                       enc_hi, enc_lo, w_hi, w_lo, ep_last, co_att);
    k_entproj<<<dim3(16, 52), 256, 0, stream>>>(enc_hi, enc_lo, w_hi, w_lo, bias, ep_hi, ep_lo);
    k_scores<<<dim3(NT3_, B_), 256, 0, stream>>>(q_enc, hint, ep_hi, ep_lo, ep_last, qlen, co_att, part);
    k_final<<<13, 256, 0, stream>>>(part, att);
}